// Round 2
// baseline (6222.058 us; speedup 1.0000x reference)
//
#include <hip/hip_runtime.h>
#include <cstdint>
#include <cstddef>

#define T_STEPS 512
#define BATCH   64
#define IN_DIM  512
#define HID     768
#define G4H     3072
#define NROWS   32768        // T*B
// h exchange: fp32 words, step-parity tag in mantissa bit0.
// plane layout (word-linear = MFMA-A fragment order): [kb 0..23][kq 0..3][m 0..31][j 0..7]
#define HPLANE  98304        // bytes per group plane (24576 words * 4B)
#define DBUFB   196608       // bytes per step-slot (2 groups)

typedef __attribute__((ext_vector_type(8))) _Float16 f16x8;
typedef __attribute__((ext_vector_type(4))) _Float16 f16x4;
typedef __attribute__((ext_vector_type(4))) float f32x4;

__device__ __forceinline__ float sigmoidf_(float z){ return 1.0f/(1.0f+expf(-z)); }
__device__ __forceinline__ unsigned short f16_bits(float v){
    return __builtin_bit_cast(unsigned short, (_Float16)v);
}

// ---------------- phase 1a: fp32 -> fp16 ----------------
__global__ void cvt_f16_kernel(const float* __restrict__ in, _Float16* __restrict__ out, int n){
    int i = blockIdx.x*256 + threadIdx.x;
    if (i < n) out[i] = (_Float16)in[i];
}

// ---------------- phase 1b: xpT[col][trow] = (x @ W^T)^T, fp16 ----------------
__global__ __launch_bounds__(256, 4) void xproj_gemm_t(
    const _Float16* __restrict__ A, const _Float16* __restrict__ B,
    unsigned short* __restrict__ CT)
{
    const int wave = threadIdx.x >> 6;
    const int lane = threadIdx.x & 63;
    const int tile = blockIdx.x*4 + wave;         // 24576 = 512 x 48
    const int mt = tile & 511;
    const int nt = tile >> 9;
    const long m0 = (long)mt*64, n0 = (long)nt*64;
    const int lr = lane & 15, lq = lane >> 4;

    f32x4 acc[4][4];
    #pragma unroll
    for (int i=0;i<4;i++)
        #pragma unroll
        for (int j=0;j<4;j++) acc[i][j] = (f32x4){0.f,0.f,0.f,0.f};

    const _Float16* Ap = A + (m0 + lr)*512 + lq*8;
    const _Float16* Bp = B + (n0 + lr)*512 + lq*8;

    for (int k0 = 0; k0 < 512; k0 += 32){
        f16x8 a[4], b[4];
        #pragma unroll
        for (int i=0;i<4;i++) a[i] = *(const f16x8*)(Ap + (long)i*16*512 + k0);
        #pragma unroll
        for (int j=0;j<4;j++) b[j] = *(const f16x8*)(Bp + (long)j*16*512 + k0);
        #pragma unroll
        for (int i=0;i<4;i++)
            #pragma unroll
            for (int j=0;j<4;j++)
                acc[i][j] = __builtin_amdgcn_mfma_f32_16x16x32_f16(a[i], b[j], acc[i][j], 0,0,0);
    }

    #pragma unroll
    for (int i=0;i<4;i++)
        #pragma unroll
        for (int j=0;j<4;j++){
            long col = n0 + 16*j + lr;
            long rb  = m0 + 16*i + lq*4;
            unsigned long long pk =
                  (unsigned long long)f16_bits(acc[i][j][0])
                | ((unsigned long long)f16_bits(acc[i][j][1]) << 16)
                | ((unsigned long long)f16_bits(acc[i][j][2]) << 32)
                | ((unsigned long long)f16_bits(acc[i][j][3]) << 48);
            *(unsigned long long*)(CT + col*NROWS + rb) = pk;
        }
}

// ---------------- phase 2: persistent scan, data-flow synchronized ----------------
// 64 blocks x 512 threads. bg=bx&1: batch half (32 rows); cb=bx>>1 owns 24 h-cols
// (96 gate-cols). NO grid barrier: h is exchanged as fp32 words tagged with step
// parity in mantissa bit0; consumers spin on the data itself (uncached loads) and
// stage to LDS fp16 the moment each 16B chunk carries the current step's tag.
// Ring depth 2 is safe: entering step t+1 requires all h(t+1) written, which
// implies all h(t) reads completed; parity distinguishes t from t-2 leftovers.
__global__ __launch_bounds__(512, 1) void lstm_scan5(
    const float* __restrict__ U,
    const float* __restrict__ bias,
    const float* __restrict__ log_alpha,
    const float* __restrict__ urand,
    const _Float16* __restrict__ xpT,
    float* __restrict__ out,
    char* __restrict__ hbuf)            // 2 slots x 2 groups x 98304 B
{
    __shared__ _Float16 sH[24576];      // 49152 B fp16, [kb][kq][m][j]
    __shared__ float sRed[2*96*33 + 4]; // gate preacts, one half per K-split wave

    const int tid = threadIdx.x;
    const int bx  = blockIdx.x;
    const int bg  = bx & 1;
    const int cb  = bx >> 1;             // 0..31
    const int hc0 = 24*cb;
    const int row0 = 32*bg;

    const int w    = tid >> 6;
    const int lane = tid & 63;
    const int ks2  = w & 1;
    const int mt   = (w >> 1) & 1;
    const int ntg  = w >> 2;             // 0..1
    const int lr   = lane & 15;
    const int kq   = lane >> 4;
    const int mrow = mt*16 + lr;

    // ---- B fragments (U slice) -> VGPRs, fp16, once ----
    f16x8 Bf[36];
    #pragma unroll
    for (int q=0;q<3;q++){
        const int c = (ntg*3+q)*16 + lr;     // 0..95
        const int g = c/24, jj = c - 24*g;
        const float* up = U + (size_t)(g*HID + hc0 + jj)*HID + kq*8;
        #pragma unroll
        for (int i=0;i<12;i++){
            const int kb = (i<6) ? (ks2*6 + i) : (12 + ks2*6 + (i-6));
            f16x8 v;
            #pragma unroll
            for (int e=0;e<8;e++) v[e] = (_Float16)up[kb*32 + e];
            Bf[q*12+i] = v;
        }
    }

    // ---- per-owner persistent state ----
    float c_state[2] = {0.f, 0.f};
    float s_cur[2]   = {0.f, 0.f};
    float bgt[2][4]  = {{0.f,0.f,0.f,0.f},{0.f,0.f,0.f,0.f}};
    float la_[2]     = {0.f, 0.f};
    #pragma unroll
    for (int s2=0;s2<2;s2++){
        const int oidx = tid + s2*512;
        if (oidx < 768){
            const int oj  = oidx >> 5;
            const int ohc = hc0 + oj;
            bgt[s2][0] = bias[ohc];
            bgt[s2][1] = bias[HID + ohc];
            bgt[s2][2] = bias[2*HID + ohc];
            bgt[s2][3] = bias[3*HID + ohc];
            la_[s2] = log_alpha[ohc];
            float uu = urand[ohc];
            float lg = (logf(uu) - log1pf(-uu) + la_[s2])*1.5f;
            s_cur[s2] = fminf(fmaxf(1.2f*sigmoidf_(lg) - 0.1f, 0.f), 1.f);
        }
    }
    __syncthreads();

#define ISSUE(ri, ii) do{ \
        const char* p_ = gsrc + (size_t)(tid + (ii)*512)*16; \
        asm volatile("global_load_dwordx4 %0, %1, off sc0 sc1" : "=v"(ri) : "v"(p_)); \
    }while(0)
#define CHECK(ri, ii) do{ \
        if (!(ready & (1u<<(ii)))){ \
            unsigned w0_=__float_as_uint(ri[0]), w1_=__float_as_uint(ri[1]); \
            unsigned w2_=__float_as_uint(ri[2]), w3_=__float_as_uint(ri[3]); \
            if ((((w0_^par)|(w1_^par)|(w2_^par)|(w3_^par)) & 1u) == 0u){ \
                ready |= 1u<<(ii); \
                f16x4 v_; \
                v_[0]=(_Float16)ri[0]; v_[1]=(_Float16)ri[1]; \
                v_[2]=(_Float16)ri[2]; v_[3]=(_Float16)ri[3]; \
                *(f16x4*)((char*)sH + (size_t)(tid + (ii)*512)*8) = v_; \
            } \
        } \
    }while(0)
#define RETRY(ri, ii) do{ if (!(ready & (1u<<(ii)))) ISSUE(ri, ii); }while(0)

    for (int t = 0; t < T_STEPS; ++t){
        const char* gsrc = hbuf + (size_t)(t&1)*DBUFB + (size_t)bg*HPLANE;
        const unsigned par = (unsigned)((t>>1)&1);

        // owner prefetch (cached; overlaps the poll)
        float xv[2][4] = {{0.f,0.f,0.f,0.f},{0.f,0.f,0.f,0.f}};
        float uun[2]   = {0.5f, 0.5f};
        #pragma unroll
        for (int s2=0;s2<2;s2++){
            const int oidx = tid + s2*512;
            if (oidx < 768){
                const int orow = oidx & 31, oj = oidx >> 5, ohc = hc0 + oj;
                const size_t trow = (size_t)t*BATCH + row0 + orow;
                xv[s2][0] = (float)xpT[(size_t)(0*HID+ohc)*NROWS + trow];
                xv[s2][1] = (float)xpT[(size_t)(1*HID+ohc)*NROWS + trow];
                xv[s2][2] = (float)xpT[(size_t)(2*HID+ohc)*NROWS + trow];
                xv[s2][3] = (float)xpT[(size_t)(3*HID+ohc)*NROWS + trow];
                if (t+1 < T_STEPS) uun[s2] = urand[(size_t)(t+1)*HID + ohc];
            }
        }

        // ---- poll h(t): each thread owns 12 x 16B chunks of the group plane ----
        f32x4 c0,c1,c2,c3,c4,c5,c6,c7,c8,c9,c10,c11;
        ISSUE(c0,0);  ISSUE(c1,1);  ISSUE(c2,2);  ISSUE(c3,3);
        ISSUE(c4,4);  ISSUE(c5,5);  ISSUE(c6,6);  ISSUE(c7,7);
        ISSUE(c8,8);  ISSUE(c9,9);  ISSUE(c10,10); ISSUE(c11,11);
        unsigned ready = 0u;
        for (;;){
            asm volatile("s_waitcnt vmcnt(0)"
                : "+v"(c0),"+v"(c1),"+v"(c2),"+v"(c3),"+v"(c4),"+v"(c5),
                  "+v"(c6),"+v"(c7),"+v"(c8),"+v"(c9),"+v"(c10),"+v"(c11)
                :: "memory");
            CHECK(c0,0);  CHECK(c1,1);  CHECK(c2,2);  CHECK(c3,3);
            CHECK(c4,4);  CHECK(c5,5);  CHECK(c6,6);  CHECK(c7,7);
            CHECK(c8,8);  CHECK(c9,9);  CHECK(c10,10); CHECK(c11,11);
            if (ready == 0xFFFu) break;
            __builtin_amdgcn_s_sleep(1);
            RETRY(c0,0);  RETRY(c1,1);  RETRY(c2,2);  RETRY(c3,3);
            RETRY(c4,4);  RETRY(c5,5);  RETRY(c6,6);  RETRY(c7,7);
            RETRY(c8,8);  RETRY(c9,9);  RETRY(c10,10); RETRY(c11,11);
        }
        __syncthreads();

        // ---- 36 MFMAs: full K in one phase, 3 N-tile acc chains ----
        f32x4 acc0 = {0.f,0.f,0.f,0.f};
        f32x4 acc1 = {0.f,0.f,0.f,0.f};
        f32x4 acc2 = {0.f,0.f,0.f,0.f};
        #pragma unroll
        for (int i=0;i<12;i++){
            const int kb = (i<6) ? (ks2*6 + i) : (12 + ks2*6 + (i-6));
            f16x8 a = *(const f16x8*)(sH + (size_t)((kb*4 + kq)*32 + mrow)*8);
            acc0 = __builtin_amdgcn_mfma_f32_16x16x32_f16(a, Bf[i],    acc0, 0,0,0);
            acc1 = __builtin_amdgcn_mfma_f32_16x16x32_f16(a, Bf[12+i], acc1, 0,0,0);
            acc2 = __builtin_amdgcn_mfma_f32_16x16x32_f16(a, Bf[24+i], acc2, 0,0,0);
        }

        // ---- write preacts: both K-split halves to disjoint sRed halves ----
        {
            const int base_r = mt*16 + kq*4;
            float* hb = sRed + ks2*3168;
            *(f32x4*)(hb + (size_t)((ntg*3+0)*16 + lr)*33 + base_r) = acc0;
            *(f32x4*)(hb + (size_t)((ntg*3+1)*16 + lr)*33 + base_r) = acc1;
            *(f32x4*)(hb + (size_t)((ntg*3+2)*16 + lr)*33 + base_r) = acc2;
        }
        __syncthreads();

        // ---- pointwise LSTM update + tagged h(t+1) stores ----
        const unsigned ptag = (unsigned)(((t+1)>>1)&1);
        #pragma unroll
        for (int s2=0;s2<2;s2++){
            const int oidx = tid + s2*512;
            if (oidx < 768){
                const int orow = oidx & 31, oj = oidx >> 5, ohc = hc0 + oj;
                float p0 = sRed[(size_t)(0*24+oj)*33 + orow] + sRed[3168 + (size_t)(0*24+oj)*33 + orow] + xv[s2][0] + bgt[s2][0];
                float p1 = sRed[(size_t)(1*24+oj)*33 + orow] + sRed[3168 + (size_t)(1*24+oj)*33 + orow] + xv[s2][1] + bgt[s2][1];
                float p2 = sRed[(size_t)(2*24+oj)*33 + orow] + sRed[3168 + (size_t)(2*24+oj)*33 + orow] + xv[s2][2] + bgt[s2][2];
                float p3 = sRed[(size_t)(3*24+oj)*33 + orow] + sRed[3168 + (size_t)(3*24+oj)*33 + orow] + xv[s2][3] + bgt[s2][3];
                const float s = s_cur[s2];
                p0 *= s; p1 *= s; p2 *= s; p3 *= s;
                float ig = sigmoidf_(p0)*s;
                float fg = sigmoidf_(p1)*s;
                float cg = tanhf(p2)*s;
                float og = sigmoidf_(p3)*s;
                c_state[s2] = fg*c_state[s2] + ig*cg;
                float h = og*tanhf(c_state[s2]);
                out[((size_t)t*BATCH + row0 + orow)*HID + ohc] = h;
                if (t+1 < T_STEPS){
                    float lg = (logf(uun[s2]) - log1pf(-uun[s2]) + la_[s2])*1.5f;
                    float sn = fminf(fmaxf(1.2f*sigmoidf_(lg) - 0.1f, 0.f), 1.f);
                    float hs = h * sn;
                    unsigned wb = (__float_as_uint(hs) & ~1u) | ptag;
                    char* dst = hbuf + (size_t)((t+1)&1)*DBUFB + (size_t)bg*HPLANE;
                    const int eo = (((ohc>>5)*4 + ((ohc>>3)&3))*32 + orow)*8 + (ohc&7);
                    asm volatile("global_store_dword %0, %1, off sc0 sc1"
                                 :: "v"(dst + 4*(size_t)eo), "v"(wb) : "memory");
                    s_cur[s2] = sn;
                }
            }
        }
        // no grid barrier: next iteration's poll self-synchronizes on the parity tags
    }
#undef ISSUE
#undef CHECK
#undef RETRY
}

extern "C" void kernel_launch(void* const* d_in, const int* in_sizes, int n_in,
                              void* d_out, int out_size, void* d_ws, size_t ws_size,
                              hipStream_t stream){
    const float* x  = (const float*)d_in[0];
    const float* W  = (const float*)d_in[1];
    const float* U  = (const float*)d_in[2];
    const float* b  = (const float*)d_in[3];
    const float* la = (const float*)d_in[4];
    const float* u  = (const float*)d_in[5];
    float* out = (float*)d_out;

    char* ws = (char*)d_ws;
    char*           hbuf = ws;                                        // 393216 B
    _Float16*       xf16 = (_Float16*)(ws + 393216);                  // 33554432 B
    _Float16*       wf16 = (_Float16*)(ws + 393216 + 33554432);       // 3145728 B
    unsigned short* xpT  = (unsigned short*)(ws + 37093376);          // 201326592 B
    // total 238419968 B <= previously proven 238424064 B footprint

    // slot0 = h(0): fp32 0.0 words, tag bit0=0 == parity(t=0) -> immediately ready.
    // slot1: byte 0x01 -> word 0x01010101, tag bit0=1 != parity(t=1)=0 -> stale.
    hipMemsetAsync(hbuf, 0, DBUFB, stream);
    hipMemsetAsync(hbuf + DBUFB, 1, DBUFB, stream);

    cvt_f16_kernel<<<65536, 256, 0, stream>>>(x, xf16, NROWS*IN_DIM);
    cvt_f16_kernel<<<6144,  256, 0, stream>>>(W, wf16, G4H*IN_DIM);
    xproj_gemm_t<<<6144, 256, 0, stream>>>(xf16, wf16, xpT);
    lstm_scan5<<<64, 512, 0, stream>>>(U, b, la, u, (const _Float16*)xpT, out, hbuf);
}

// Round 3
// 4395.050 us; speedup vs baseline: 1.4157x; 1.4157x over previous
//
#include <hip/hip_runtime.h>
#include <cstdint>
#include <cstddef>

#define T_STEPS 512
#define BATCH   64
#define IN_DIM  512
#define HID     768
#define G4H     3072
#define NROWS   32768        // T*B
// h exchange: fp16 plane per group, MFMA-A fragment-linear == [c8 0..95][row 0..31][j 0..7]
#define HPLANE  49152        // bytes per group plane (768*32 fp16)
#define DBUFB   98304        // bytes per step-slot (2 groups)

typedef __attribute__((ext_vector_type(8))) _Float16 f16x8;
typedef __attribute__((ext_vector_type(4))) float f32x4;

__device__ __forceinline__ float sigmoidf_(float z){ return 1.0f/(1.0f+expf(-z)); }
__device__ __forceinline__ unsigned short f16_bits(float v){
    return __builtin_bit_cast(unsigned short, (_Float16)v);
}

// ---------------- phase 1a: fp32 -> fp16 ----------------
__global__ void cvt_f16_kernel(const float* __restrict__ in, _Float16* __restrict__ out, int n){
    int i = blockIdx.x*256 + threadIdx.x;
    if (i < n) out[i] = (_Float16)in[i];
}

// ---------------- phase 1b: xpT[col][trow] = (x @ W^T)^T, fp16 ----------------
__global__ __launch_bounds__(256, 4) void xproj_gemm_t(
    const _Float16* __restrict__ A, const _Float16* __restrict__ B,
    unsigned short* __restrict__ CT)
{
    const int wave = threadIdx.x >> 6;
    const int lane = threadIdx.x & 63;
    const int tile = blockIdx.x*4 + wave;         // 24576 = 512 x 48
    const int mt = tile & 511;
    const int nt = tile >> 9;
    const long m0 = (long)mt*64, n0 = (long)nt*64;
    const int lr = lane & 15, lq = lane >> 4;

    f32x4 acc[4][4];
    #pragma unroll
    for (int i=0;i<4;i++)
        #pragma unroll
        for (int j=0;j<4;j++) acc[i][j] = (f32x4){0.f,0.f,0.f,0.f};

    const _Float16* Ap = A + (m0 + lr)*512 + lq*8;
    const _Float16* Bp = B + (n0 + lr)*512 + lq*8;

    for (int k0 = 0; k0 < 512; k0 += 32){
        f16x8 a[4], b[4];
        #pragma unroll
        for (int i=0;i<4;i++) a[i] = *(const f16x8*)(Ap + (long)i*16*512 + k0);
        #pragma unroll
        for (int j=0;j<4;j++) b[j] = *(const f16x8*)(Bp + (long)j*16*512 + k0);
        #pragma unroll
        for (int i=0;i<4;i++)
            #pragma unroll
            for (int j=0;j<4;j++)
                acc[i][j] = __builtin_amdgcn_mfma_f32_16x16x32_f16(a[i], b[j], acc[i][j], 0,0,0);
    }

    #pragma unroll
    for (int i=0;i<4;i++)
        #pragma unroll
        for (int j=0;j<4;j++){
            long col = n0 + 16*j + lr;
            long rb  = m0 + 16*i + lq*4;
            unsigned long long pk =
                  (unsigned long long)f16_bits(acc[i][j][0])
                | ((unsigned long long)f16_bits(acc[i][j][1]) << 16)
                | ((unsigned long long)f16_bits(acc[i][j][2]) << 32)
                | ((unsigned long long)f16_bits(acc[i][j][3]) << 48);
            *(unsigned long long*)(CT + col*NROWS + rb) = pk;
        }
}

// ---------------- phase 2: persistent scan, flag-released fp16 exchange ----------------
// 64 blocks x 512 threads. bg=bx&1: batch half (32 rows); cb=bx>>1 owns 24 h-cols.
// Sync per step: producer {coalesced h stores (sc0 sc1) -> vmcnt(0) -> flag[cb]=t+1};
// consumer wave0 polls the 32 per-producer flags (one lane-parallel load per poll),
// then every lane loads its 12 MFMA A-fragments DIRECTLY from the plane (no LDS
// staging). Ring depth 2: entering step t needs all flags>=t (h(t) written), which
// implies every block finished step t-1, hence all h(t-1) reads are done before
// slot (t+1)&1 == (t-1)&1 is overwritten.
__global__ __launch_bounds__(512, 1) void lstm_scan6(
    const float* __restrict__ U,
    const float* __restrict__ bias,
    const float* __restrict__ log_alpha,
    const float* __restrict__ urand,
    const _Float16* __restrict__ xpT,
    float* __restrict__ out,
    char* __restrict__ hbuf,            // 2 slots x 2 groups x 49152 B
    unsigned int* __restrict__ flags)   // 2 groups x 64 dwords (32 used)
{
    __shared__ float sRed[2*3168 + 4];  // gate preacts [ks2][c 0..95][row], stride 33

    const int tid = threadIdx.x;
    const int bx  = blockIdx.x;
    const int bg  = bx & 1;
    const int cb  = bx >> 1;             // 0..31
    const int hc0 = 24*cb;
    const int row0 = 32*bg;

    const int w    = tid >> 6;
    const int lane = tid & 63;
    const int ks2  = w & 1;
    const int mt   = (w >> 1) & 1;
    const int ntg  = w >> 2;             // 0..1
    const int lr   = lane & 15;
    const int kq   = lane >> 4;
    const int mrow = mt*16 + lr;

    // ---- B fragments (U slice) -> registers, fp16, once ----
    f16x8 Bf[36];
    #pragma unroll
    for (int q=0;q<3;q++){
        const int c = (ntg*3+q)*16 + lr;     // 0..95
        const int g = c/24, jj = c - 24*g;
        const float* up = U + (size_t)(g*HID + hc0 + jj)*HID + kq*8;
        #pragma unroll
        for (int i=0;i<12;i++){
            const int kb = (i<6) ? (ks2*6 + i) : (12 + ks2*6 + (i-6));
            f16x8 v;
            #pragma unroll
            for (int e=0;e<8;e++) v[e] = (_Float16)up[kb*32 + e];
            Bf[q*12+i] = v;
        }
    }

    // ---- per-owner persistent state (j-fastest mapping: coalesced h stores) ----
    // slot s2: oidx = tid + s2*512; j=oidx&7, orow=(oidx>>3)&31, c8L=oidx>>8
    float c_state[2] = {0.f, 0.f};
    float s_cur[2]   = {0.f, 0.f};
    float bgt[2][4]  = {{0.f,0.f,0.f,0.f},{0.f,0.f,0.f,0.f}};
    float la_[2]     = {0.f, 0.f};
    #pragma unroll
    for (int s2=0;s2<2;s2++){
        const int oidx = tid + s2*512;
        if (oidx < 768){
            const int oj  = (oidx>>8)*8 + (oidx&7);   // col-within-block 0..23
            const int ohc = hc0 + oj;
            bgt[s2][0] = bias[ohc];
            bgt[s2][1] = bias[HID + ohc];
            bgt[s2][2] = bias[2*HID + ohc];
            bgt[s2][3] = bias[3*HID + ohc];
            la_[s2] = log_alpha[ohc];
            float uu = urand[ohc];
            float lg = (logf(uu) - log1pf(-uu) + la_[s2])*1.5f;
            s_cur[s2] = fminf(fmaxf(1.2f*sigmoidf_(lg) - 0.1f, 0.f), 1.f);
        }
    }
    __syncthreads();

    const unsigned int* fpoll = flags + bg*64 + (lane & 31);

    for (int t = 0; t < T_STEPS; ++t){
        const char* gsrc = hbuf + (size_t)(t&1)*DBUFB + (size_t)bg*HPLANE;

        // owner prefetch (cached loads, issued before poll; latency absorbed there)
        float xv[2][4] = {{0.f,0.f,0.f,0.f},{0.f,0.f,0.f,0.f}};
        float uun[2]   = {0.5f, 0.5f};
        #pragma unroll
        for (int s2=0;s2<2;s2++){
            const int oidx = tid + s2*512;
            if (oidx < 768){
                const int orow = (oidx>>3)&31;
                const int oj   = (oidx>>8)*8 + (oidx&7);
                const int ohc  = hc0 + oj;
                const size_t trow = (size_t)t*BATCH + row0 + orow;
                xv[s2][0] = (float)xpT[(size_t)(0*HID+ohc)*NROWS + trow];
                xv[s2][1] = (float)xpT[(size_t)(1*HID+ohc)*NROWS + trow];
                xv[s2][2] = (float)xpT[(size_t)(2*HID+ohc)*NROWS + trow];
                xv[s2][3] = (float)xpT[(size_t)(3*HID+ohc)*NROWS + trow];
                if (t+1 < T_STEPS) uun[s2] = urand[(size_t)(t+1)*HID + ohc];
            }
        }

        // ---- wave 0 polls the 32 per-producer flags (h(t) release) ----
        if (w == 0){
            for (;;){
                unsigned f;
                asm volatile("global_load_dword %0, %1, off sc0 sc1" : "=v"(f) : "v"(fpoll));
                asm volatile("s_waitcnt vmcnt(0)" : "+v"(f) :: "memory");
                if (__all((int)f >= t)) break;
            }
        }
        __syncthreads();

        // ---- A fragments: direct uncached loads from the plane (no LDS) ----
        f32x4 ar[12];
        #pragma unroll
        for (int i=0;i<12;i++){
            const int kb = (i<6) ? (ks2*6 + i) : (12 + ks2*6 + (i-6));
            const char* ap = gsrc + kb*2048 + kq*512 + mrow*16;
            asm volatile("global_load_dwordx4 %0, %1, off sc0 sc1" : "=v"(ar[i]) : "v"(ap));
        }
        asm volatile("s_waitcnt vmcnt(0)"
            : "+v"(ar[0]),"+v"(ar[1]),"+v"(ar[2]),"+v"(ar[3]),"+v"(ar[4]),"+v"(ar[5]),
              "+v"(ar[6]),"+v"(ar[7]),"+v"(ar[8]),"+v"(ar[9]),"+v"(ar[10]),"+v"(ar[11])
            :: "memory");
        __builtin_amdgcn_sched_barrier(0);

        // ---- 36 MFMAs: 3 N-tile acc chains ----
        f32x4 acc0 = {0.f,0.f,0.f,0.f};
        f32x4 acc1 = {0.f,0.f,0.f,0.f};
        f32x4 acc2 = {0.f,0.f,0.f,0.f};
        #pragma unroll
        for (int i=0;i<12;i++){
            f16x8 a = __builtin_bit_cast(f16x8, ar[i]);
            acc0 = __builtin_amdgcn_mfma_f32_16x16x32_f16(a, Bf[i],    acc0, 0,0,0);
            acc1 = __builtin_amdgcn_mfma_f32_16x16x32_f16(a, Bf[12+i], acc1, 0,0,0);
            acc2 = __builtin_amdgcn_mfma_f32_16x16x32_f16(a, Bf[24+i], acc2, 0,0,0);
        }

        // ---- write preacts: both K-split halves to disjoint sRed halves ----
        {
            const int base_r = mt*16 + kq*4;
            float* hb = sRed + ks2*3168;
            *(f32x4*)(hb + (size_t)((ntg*3+0)*16 + lr)*33 + base_r) = acc0;
            *(f32x4*)(hb + (size_t)((ntg*3+1)*16 + lr)*33 + base_r) = acc1;
            *(f32x4*)(hb + (size_t)((ntg*3+2)*16 + lr)*33 + base_r) = acc2;
        }
        __syncthreads();

        // ---- pointwise LSTM update + coalesced h(t+1) stores ----
        #pragma unroll
        for (int s2=0;s2<2;s2++){
            const int oidx = tid + s2*512;
            if (oidx < 768){
                const int j_   = oidx & 7;
                const int orow = (oidx>>3)&31;
                const int c8L  = oidx>>8;
                const int oj   = c8L*8 + j_;
                const int ohc  = hc0 + oj;
                float p0 = sRed[(size_t)(0*24+oj)*33 + orow] + sRed[3168 + (size_t)(0*24+oj)*33 + orow] + xv[s2][0] + bgt[s2][0];
                float p1 = sRed[(size_t)(1*24+oj)*33 + orow] + sRed[3168 + (size_t)(1*24+oj)*33 + orow] + xv[s2][1] + bgt[s2][1];
                float p2 = sRed[(size_t)(2*24+oj)*33 + orow] + sRed[3168 + (size_t)(2*24+oj)*33 + orow] + xv[s2][2] + bgt[s2][2];
                float p3 = sRed[(size_t)(3*24+oj)*33 + orow] + sRed[3168 + (size_t)(3*24+oj)*33 + orow] + xv[s2][3] + bgt[s2][3];
                const float s = s_cur[s2];
                p0 *= s; p1 *= s; p2 *= s; p3 *= s;
                float ig = sigmoidf_(p0)*s;
                float fg = sigmoidf_(p1)*s;
                float cg = tanhf(p2)*s;
                float og = sigmoidf_(p3)*s;
                c_state[s2] = fg*c_state[s2] + ig*cg;
                float h = og*tanhf(c_state[s2]);
                out[((size_t)t*BATCH + row0 + orow)*HID + ohc] = h;
                if (t+1 < T_STEPS){
                    float lg = (logf(uun[s2]) - log1pf(-uun[s2]) + la_[s2])*1.5f;
                    float sn = fminf(fmaxf(1.2f*sigmoidf_(lg) - 0.1f, 0.f), 1.f);
                    float hs = h * sn;
                    unsigned int hv = f16_bits(hs);
                    // plane elem ((3*cb + c8L)*32 + orow)*8 + j : j-fastest => wave stores 128B contiguous
                    char* dst = hbuf + (size_t)((t+1)&1)*DBUFB + (size_t)bg*HPLANE
                              + 2*(size_t)((((3*cb + c8L)*32) + orow)*8 + j_);
                    asm volatile("global_store_short %0, %1, off sc0 sc1"
                                 :: "v"(dst), "v"(hv) : "memory");
                    s_cur[s2] = sn;
                }
            }
        }

        // ---- release: drain h stores, then per-producer flag ----
        if (t+1 < T_STEPS){
            asm volatile("s_waitcnt vmcnt(0)" ::: "memory");
            __syncthreads();
            if (tid == 0){
                unsigned v = (unsigned)(t+1);
                const unsigned int* fst = flags + bg*64 + cb;
                asm volatile("global_store_dword %0, %1, off sc0 sc1"
                             :: "v"(fst), "v"(v) : "memory");
            }
        }
    }
}

extern "C" void kernel_launch(void* const* d_in, const int* in_sizes, int n_in,
                              void* d_out, int out_size, void* d_ws, size_t ws_size,
                              hipStream_t stream){
    const float* x  = (const float*)d_in[0];
    const float* W  = (const float*)d_in[1];
    const float* U  = (const float*)d_in[2];
    const float* b  = (const float*)d_in[3];
    const float* la = (const float*)d_in[4];
    const float* u  = (const float*)d_in[5];
    float* out = (float*)d_out;

    char* ws = (char*)d_ws;
    char*           hbuf  = ws;                                       // 196608 B (2 slots)
    unsigned int*   flags = (unsigned int*)(ws + 196608);             // 512 B
    _Float16*       xf16  = (_Float16*)(ws + 197120);                 // 33554432 B
    _Float16*       wf16  = (_Float16*)(ws + 197120 + 33554432);      // 3145728 B
    unsigned short* xpT   = (unsigned short*)(ws + 36897280);         // 201326592 B
    // total 238223872 B <= previously proven 238424064 B footprint

    // slot0 = h(0) = fp16 zeros; flags = 0 (step-0 poll passes immediately).
    hipMemsetAsync(ws, 0, 197120, stream);

    cvt_f16_kernel<<<65536, 256, 0, stream>>>(x, xf16, NROWS*IN_DIM);
    cvt_f16_kernel<<<6144,  256, 0, stream>>>(W, wf16, G4H*IN_DIM);
    xproj_gemm_t<<<6144, 256, 0, stream>>>(xf16, wf16, xpT);
    lstm_scan6<<<64, 512, 0, stream>>>(U, b, la, u, (const _Float16*)xpT, out, hbuf, flags);
}

// Round 7
// 4308.522 us; speedup vs baseline: 1.4441x; 1.0201x over previous
//
#include <hip/hip_runtime.h>
#include <cstdint>
#include <cstddef>

#define T_STEPS 512
#define BATCH   64
#define IN_DIM  512
#define HID     768
#define G4H     3072
#define NROWS   32768        // T*B
// h exchange: fp16 plane per batch-group, MFMA-A fragment-linear:
// elem ((ohc>>3)*32 + row)*8 + (ohc&7)  ==  [c8 0..95][row 0..31][j 0..7]
#define HPLANE  49152        // bytes per group plane (768*32 fp16)
#define DBUFB   98304        // bytes per step-slot (2 groups)

typedef __attribute__((ext_vector_type(8))) _Float16 f16x8;
typedef __attribute__((ext_vector_type(4))) float f32x4;

__device__ __forceinline__ float sigmoidf_(float z){ return 1.0f/(1.0f+expf(-z)); }
__device__ __forceinline__ unsigned short f16_bits(float v){
    return __builtin_bit_cast(unsigned short, (_Float16)v);
}

// ---------------- phase 1a: fp32 -> fp16 ----------------
__global__ void cvt_f16_kernel(const float* __restrict__ in, _Float16* __restrict__ out, int n){
    int i = blockIdx.x*256 + threadIdx.x;
    if (i < n) out[i] = (_Float16)in[i];
}

// ---------------- phase 1b: xpT[col][trow] = (x @ W^T)^T, fp16 (r1-proven) ----------------
__global__ __launch_bounds__(256, 4) void xproj_gemm_t(
    const _Float16* __restrict__ A, const _Float16* __restrict__ B,
    unsigned short* __restrict__ CT)
{
    const int wave = threadIdx.x >> 6;
    const int lane = threadIdx.x & 63;
    const int tile = blockIdx.x*4 + wave;         // 24576 = 512 x 48
    const int mt = tile & 511;
    const int nt = tile >> 9;
    const long m0 = (long)mt*64, n0 = (long)nt*64;
    const int lr = lane & 15, lq = lane >> 4;

    f32x4 acc[4][4];
    #pragma unroll
    for (int i=0;i<4;i++)
        #pragma unroll
        for (int j=0;j<4;j++) acc[i][j] = (f32x4){0.f,0.f,0.f,0.f};

    const _Float16* Ap = A + (m0 + lr)*512 + lq*8;
    const _Float16* Bp = B + (n0 + lr)*512 + lq*8;

    for (int k0 = 0; k0 < 512; k0 += 32){
        f16x8 a[4], b[4];
        #pragma unroll
        for (int i=0;i<4;i++) a[i] = *(const f16x8*)(Ap + (long)i*16*512 + k0);
        #pragma unroll
        for (int j=0;j<4;j++) b[j] = *(const f16x8*)(Bp + (long)j*16*512 + k0);
        #pragma unroll
        for (int i=0;i<4;i++)
            #pragma unroll
            for (int j=0;j<4;j++)
                acc[i][j] = __builtin_amdgcn_mfma_f32_16x16x32_f16(a[i], b[j], acc[i][j], 0,0,0);
    }

    #pragma unroll
    for (int i=0;i<4;i++)
        #pragma unroll
        for (int j=0;j<4;j++){
            long col = n0 + 16*j + lr;
            long rb  = m0 + 16*i + lq*4;
            unsigned long long pk =
                  (unsigned long long)f16_bits(acc[i][j][0])
                | ((unsigned long long)f16_bits(acc[i][j][1]) << 16)
                | ((unsigned long long)f16_bits(acc[i][j][2]) << 32)
                | ((unsigned long long)f16_bits(acc[i][j][3]) << 48);
            *(unsigned long long*)(CT + col*NROWS + rb) = pk;
        }
}

// ---------------- phase 2: persistent scan ----------------
// 64 blocks x 512 threads. bg=bx&1: batch half (32 rows); cb=bx>>1 owns 24 h-cols
// (96 gate-cols = 6 N-tiles). Waves: ks4=w&3 (4-way K-split, 6 kb each), mt=w>>2
// (M-tile). Each thread loads its 6 MFMA A-fragments DIRECTLY from the plane
// (uncached sc0 sc1; plane read exactly once per block — no LDS staging, no
// staging syncs). U B-fragments (36 x f16x8) live in VGPRs for all 512 steps.
// Sync: r0/r1-proven striped-counter grid barrier per step (4 cells per group).
__global__ __launch_bounds__(512, 1) void lstm_scan10(
    const float* __restrict__ U,
    const float* __restrict__ bias,
    const float* __restrict__ log_alpha,
    const float* __restrict__ urand,
    const _Float16* __restrict__ xpT,
    float* __restrict__ out,
    char* __restrict__ hbuf,            // 2 slots x 2 groups x 49152 B
    unsigned int* __restrict__ bar)
{
    __shared__ float sRed[4*96*33 + 4]; // K-split partials [ks4][c 0..95][row], stride 33

    const int tid = threadIdx.x;
    const int bx  = blockIdx.x;
    const int bg  = bx & 1;
    const int cb  = bx >> 1;             // 0..31
    const int hc0 = 24*cb;
    const int row0 = 32*bg;

    const int w    = tid >> 6;
    const int lane = tid & 63;
    const int ks4  = w & 3;              // kb in [ks4*6, ks4*6+6)
    const int mt   = w >> 2;             // M-tile 0..1
    const int lr   = lane & 15;
    const int kq   = lane >> 4;
    const int mrow = mt*16 + lr;

    // ---- B fragments (U slice) -> VGPRs, fp16, once: 6 N-tiles x 6 kb ----
    f16x8 Bf[36];
    #pragma unroll
    for (int q=0;q<6;q++){
        const int c = q*16 + lr;             // gate-col within block, 0..95
        const int gi = c/24, jj = c - 24*gi;
        const float* up = U + (size_t)(gi*HID + hc0 + jj)*HID + kq*8;
        #pragma unroll
        for (int i=0;i<6;i++){
            const int kb = ks4*6 + i;
            f16x8 v;
            #pragma unroll
            for (int e=0;e<8;e++) v[e] = (_Float16)up[kb*32 + e];
            Bf[q*6+i] = v;
        }
    }

    // ---- per-owner persistent state, j-fastest mapping (coalesced h stores) ----
    // slot s2: oidx = tid + s2*512; j=oidx&7, orow=(oidx>>3)&31, c8L=oidx>>8
    float c_state[2] = {0.f, 0.f};
    float s_cur[2]   = {0.f, 0.f};
    float bgt[2][4]  = {{0.f,0.f,0.f,0.f},{0.f,0.f,0.f,0.f}};
    float la_[2]     = {0.f, 0.f};
    #pragma unroll
    for (int s2=0;s2<2;s2++){
        const int oidx = tid + s2*512;
        if (oidx < 768){
            const int oj  = (oidx>>8)*8 + (oidx&7);   // col-within-block 0..23
            const int ohc = hc0 + oj;
            bgt[s2][0] = bias[ohc];
            bgt[s2][1] = bias[HID + ohc];
            bgt[s2][2] = bias[2*HID + ohc];
            bgt[s2][3] = bias[3*HID + ohc];
            la_[s2] = log_alpha[ohc];
            float uu = urand[ohc];
            float lg = (logf(uu) - log1pf(-uu) + la_[s2])*1.5f;
            s_cur[s2] = fminf(fmaxf(1.2f*sigmoidf_(lg) - 0.1f, 0.f), 1.f);
        }
    }
    __syncthreads();

    for (int t = 0; t < T_STEPS; ++t){
        const char* gsrc = hbuf + (size_t)(t&1)*DBUFB + (size_t)bg*HPLANE;

        // owner prefetch (cached; constant data, overlaps the A-loads)
        float xv[2][4] = {{0.f,0.f,0.f,0.f},{0.f,0.f,0.f,0.f}};
        float uun[2]   = {0.5f, 0.5f};
        #pragma unroll
        for (int s2=0;s2<2;s2++){
            const int oidx = tid + s2*512;
            if (oidx < 768){
                const int orow = (oidx>>3)&31;
                const int oj   = (oidx>>8)*8 + (oidx&7);
                const int ohc  = hc0 + oj;
                const size_t trow = (size_t)t*BATCH + row0 + orow;
                xv[s2][0] = (float)xpT[(size_t)(0*HID+ohc)*NROWS + trow];
                xv[s2][1] = (float)xpT[(size_t)(1*HID+ohc)*NROWS + trow];
                xv[s2][2] = (float)xpT[(size_t)(2*HID+ohc)*NROWS + trow];
                xv[s2][3] = (float)xpT[(size_t)(3*HID+ohc)*NROWS + trow];
                if (t+1 < T_STEPS) uun[s2] = urand[(size_t)(t+1)*HID + ohc];
            }
        }

        // ---- A fragments: 6 direct uncached loads (h(t) guaranteed by barrier) ----
        f32x4 ar[6];
        #pragma unroll
        for (int i=0;i<6;i++){
            const int kb = ks4*6 + i;
            const char* ap = gsrc + (size_t)(((kb*4 + kq)*32 + mrow)*16);
            asm volatile("global_load_dwordx4 %0, %1, off sc0 sc1" : "=v"(ar[i]) : "v"(ap));
        }
        asm volatile("s_waitcnt vmcnt(0)"
            : "+v"(ar[0]),"+v"(ar[1]),"+v"(ar[2]),"+v"(ar[3]),"+v"(ar[4]),"+v"(ar[5])
            :: "memory");
        __builtin_amdgcn_sched_barrier(0);

        // ---- 36 MFMAs: 6 N-tile acc chains x 6 K-blocks ----
        f32x4 acc[6];
        #pragma unroll
        for (int q=0;q<6;q++) acc[q] = (f32x4){0.f,0.f,0.f,0.f};
        #pragma unroll
        for (int i=0;i<6;i++){
            f16x8 a = __builtin_bit_cast(f16x8, ar[i]);
            #pragma unroll
            for (int q=0;q<6;q++)
                acc[q] = __builtin_amdgcn_mfma_f32_16x16x32_f16(a, Bf[q*6+i], acc[q], 0,0,0);
        }

        // ---- K-split partials to LDS (disjoint regions; summed in pointwise) ----
        #pragma unroll
        for (int q=0;q<6;q++){
            const int c = q*16 + lr;
            float* rp = sRed + (size_t)(ks4*96 + c)*33 + mt*16 + kq*4;
            #pragma unroll
            for (int k=0;k<4;k++) rp[k] = acc[q][k];
        }
        __syncthreads();

        // ---- pointwise LSTM update (768 outputs; tid<256 own two) ----
        #pragma unroll
        for (int s2=0;s2<2;s2++){
            const int oidx = tid + s2*512;
            if (oidx < 768){
                const int j_   = oidx & 7;
                const int orow = (oidx>>3)&31;
                const int c8L  = oidx>>8;
                const int colL = c8L*8 + j_;
                const int ohc  = hc0 + colL;
                float p0 = xv[s2][0] + bgt[s2][0];
                float p1 = xv[s2][1] + bgt[s2][1];
                float p2 = xv[s2][2] + bgt[s2][2];
                float p3 = xv[s2][3] + bgt[s2][3];
                #pragma unroll
                for (int ks=0;ks<4;ks++){
                    p0 += sRed[(size_t)(ks*96 + 0*24 + colL)*33 + orow];
                    p1 += sRed[(size_t)(ks*96 + 1*24 + colL)*33 + orow];
                    p2 += sRed[(size_t)(ks*96 + 2*24 + colL)*33 + orow];
                    p3 += sRed[(size_t)(ks*96 + 3*24 + colL)*33 + orow];
                }
                const float s = s_cur[s2];
                p0 *= s; p1 *= s; p2 *= s; p3 *= s;
                float ig = sigmoidf_(p0)*s;
                float fg = sigmoidf_(p1)*s;
                float cg = tanhf(p2)*s;
                float og = sigmoidf_(p3)*s;
                c_state[s2] = fg*c_state[s2] + ig*cg;
                float h = og*tanhf(c_state[s2]);
                out[((size_t)t*BATCH + row0 + orow)*HID + ohc] = h;
                if (t+1 < T_STEPS){
                    float lg = (logf(uun[s2]) - log1pf(-uun[s2]) + la_[s2])*1.5f;
                    float sn = fminf(fmaxf(1.2f*sigmoidf_(lg) - 0.1f, 0.f), 1.f);
                    float hs = h * sn;
                    unsigned int hv = f16_bits(hs);
                    // elem = ((ohc>>3)*32 + orow)*8 + (ohc&7) = (3cb+c8L)*256 + orow*8 + j
                    // j-fastest owners => each wave stores one 128B contiguous run
                    char* dst = hbuf + (size_t)((t+1)&1)*DBUFB + (size_t)bg*HPLANE
                              + 2*(size_t)(((3*cb + c8L)*32 + orow)*8 + j_);
                    asm volatile("global_store_short %0, %1, off sc0 sc1"
                                 :: "v"(dst), "v"(hv) : "memory");
                    s_cur[s2] = sn;
                }
            }
        }

        // ---- grid barrier (32 blocks per group, 4 striped counters; r0/r1-proven) ----
        if (t+1 < T_STEPS){
            asm volatile("s_waitcnt vmcnt(0)" ::: "memory");  // h stores at MALL
            __syncthreads();
            if (tid == 0){
                const unsigned cell = (unsigned)((bg*4 + (cb&3))*32);
                __hip_atomic_fetch_add(bar + cell, 1u, __ATOMIC_RELAXED, __HIP_MEMORY_SCOPE_AGENT);
                const unsigned tgt = (unsigned)(t+1)*32u;
                for (;;){
                    unsigned ssum = 0;
                    #pragma unroll
                    for (int c2=0;c2<4;c2++)
                        ssum += __hip_atomic_load(bar + (bg*4+c2)*32, __ATOMIC_RELAXED, __HIP_MEMORY_SCOPE_AGENT);
                    if (ssum >= tgt) break;
                    __builtin_amdgcn_s_sleep(1);
                }
            }
            __syncthreads();
        }
    }
}

extern "C" void kernel_launch(void* const* d_in, const int* in_sizes, int n_in,
                              void* d_out, int out_size, void* d_ws, size_t ws_size,
                              hipStream_t stream){
    const float* x  = (const float*)d_in[0];
    const float* W  = (const float*)d_in[1];
    const float* U  = (const float*)d_in[2];
    const float* b  = (const float*)d_in[3];
    const float* la = (const float*)d_in[4];
    const float* u  = (const float*)d_in[5];
    float* out = (float*)d_out;

    char* ws = (char*)d_ws;
    char*           hbuf = ws;                                        // 196608 B (2 slots)
    unsigned int*   bar  = (unsigned int*)(ws + 196608);              // 1024 B used
    _Float16*       xf16 = (_Float16*)(ws + 200704);                  // 33554432 B
    _Float16*       wf16 = (_Float16*)(ws + 200704 + 33554432);       // 3145728 B
    unsigned short* xpT  = (unsigned short*)(ws + 36900864);          // 201326592 B
    // total 238227456 B <= previously proven 238424064 B footprint

    hipMemsetAsync(d_ws, 0, 200704, stream);   // zero hbuf (h0=0) + barrier

    cvt_f16_kernel<<<65536, 256, 0, stream>>>(x, xf16, NROWS*IN_DIM);
    cvt_f16_kernel<<<6144,  256, 0, stream>>>(W, wf16, G4H*IN_DIM);
    xproj_gemm_t<<<6144, 256, 0, stream>>>(xf16, wf16, xpT);
    lstm_scan10<<<64, 512, 0, stream>>>(U, b, la, u, (const _Float16*)xpT, out, hbuf, bar);
}

// Round 8
// 2517.835 us; speedup vs baseline: 2.4712x; 1.7112x over previous
//
#include <hip/hip_runtime.h>
#include <cstdint>
#include <cstddef>

#define T_STEPS 512
#define BATCH   64
#define IN_DIM  512
#define HID     768
#define G4H     3072
#define NROWS   32768        // T*B
// h exchange: fp16 plane per batch-group, MFMA-A fragment-linear:
// elem ((ohc>>3)*32 + row)*8 + (ohc&7)  ==  [c8 0..95][row 0..31][j 0..7]
#define HPLANE  49152        // bytes per group plane (768*32 fp16)
#define DBUFB   98304        // bytes per step-slot (2 groups)

typedef __attribute__((ext_vector_type(8))) _Float16 f16x8;
typedef __attribute__((ext_vector_type(4))) float f32x4;

__device__ __forceinline__ float sigmoidf_(float z){ return 1.0f/(1.0f+expf(-z)); }
__device__ __forceinline__ unsigned short f16_bits(float v){
    return __builtin_bit_cast(unsigned short, (_Float16)v);
}
__device__ __forceinline__ float h16_to_f(unsigned u){
    return (float)__builtin_bit_cast(_Float16, (unsigned short)(u & 0xffffu));
}

// ---------------- phase 1a: fp32 -> fp16 ----------------
__global__ void cvt_f16_kernel(const float* __restrict__ in, _Float16* __restrict__ out, int n){
    int i = blockIdx.x*256 + threadIdx.x;
    if (i < n) out[i] = (_Float16)in[i];
}

// ---------------- phase 1c: hard-concrete gate s_all[t][h], once ----------------
__global__ void gate_s_kernel(const float* __restrict__ u, const float* __restrict__ la,
                              float* __restrict__ s_all, int n){
    int i = blockIdx.x*256 + threadIdx.x;
    if (i < n){
        int h = i % HID;
        float uu = u[i];
        float lg = (logf(uu) - log1pf(-uu) + la[h]) * 1.5f;
        s_all[i] = fminf(fmaxf(1.2f*sigmoidf_(lg) - 0.1f, 0.f), 1.f);
    }
}

// ---------------- phase 1b: xpT[col][trow] = (x @ W^T)^T, fp16 (r1-proven) ----------------
__global__ __launch_bounds__(256, 4) void xproj_gemm_t(
    const _Float16* __restrict__ A, const _Float16* __restrict__ B,
    unsigned short* __restrict__ CT)
{
    const int wave = threadIdx.x >> 6;
    const int lane = threadIdx.x & 63;
    const int tile = blockIdx.x*4 + wave;         // 24576 = 512 x 48
    const int mt = tile & 511;
    const int nt = tile >> 9;
    const long m0 = (long)mt*64, n0 = (long)nt*64;
    const int lr = lane & 15, lq = lane >> 4;

    f32x4 acc[4][4];
    #pragma unroll
    for (int i=0;i<4;i++)
        #pragma unroll
        for (int j=0;j<4;j++) acc[i][j] = (f32x4){0.f,0.f,0.f,0.f};

    const _Float16* Ap = A + (m0 + lr)*512 + lq*8;
    const _Float16* Bp = B + (n0 + lr)*512 + lq*8;

    for (int k0 = 0; k0 < 512; k0 += 32){
        f16x8 a[4], b[4];
        #pragma unroll
        for (int i=0;i<4;i++) a[i] = *(const f16x8*)(Ap + (long)i*16*512 + k0);
        #pragma unroll
        for (int j=0;j<4;j++) b[j] = *(const f16x8*)(Bp + (long)j*16*512 + k0);
        #pragma unroll
        for (int i=0;i<4;i++)
            #pragma unroll
            for (int j=0;j<4;j++)
                acc[i][j] = __builtin_amdgcn_mfma_f32_16x16x32_f16(a[i], b[j], acc[i][j], 0,0,0);
    }

    #pragma unroll
    for (int i=0;i<4;i++)
        #pragma unroll
        for (int j=0;j<4;j++){
            long col = n0 + 16*j + lr;
            long rb  = m0 + 16*i + lq*4;
            unsigned long long pk =
                  (unsigned long long)f16_bits(acc[i][j][0])
                | ((unsigned long long)f16_bits(acc[i][j][1]) << 16)
                | ((unsigned long long)f16_bits(acc[i][j][2]) << 32)
                | ((unsigned long long)f16_bits(acc[i][j][3]) << 48);
            *(unsigned long long*)(CT + col*NROWS + rb) = pk;
        }
}

// ---------------- phase 2: persistent scan (r0 shape + fp16 + direct loads) ----------------
// 256 blocks x 512 threads, LDS-pinned 1 block/CU. bg=bx&1: batch half (32 rows);
// cb=bx>>1 owns 6 h-cols (24 gate-cols padded to 32 = 2 N-tiles).
// Waves: ks2=w&1 (12 kb each), mt=(w>>1)&1, nt=(w>>2)&1. 12 MFMAs/wave/step.
// A-fragments load DIRECTLY to VGPRs from the fp16 plane (no LDS staging).
// xpT/s_all for step t+1 prefetched under the barrier wait.
// Sync: r0-proven striped-counter grid barrier (128 arrivals/group, 4 cells).
__global__ __launch_bounds__(512, 1) void lstm_scan11(
    const float* __restrict__ U,
    const float* __restrict__ bias,
    const float* __restrict__ s_all,
    const _Float16* __restrict__ xpT,
    float* __restrict__ out,
    char* __restrict__ hbuf,            // 2 slots x 2 groups x 49152 B
    unsigned int* __restrict__ bar)
{
    __shared__ float sRed[2*32*33 + 4]; // K-split partials [ks2][c 0..31][row], stride 33
    __shared__ char  sPad[77824];       // occupancy pin: ~86KB total => 1 block/CU

    const int tid = threadIdx.x;
    const int bx  = blockIdx.x;
    const int bg  = bx & 1;
    const int cb  = bx >> 1;             // 0..127
    const int hc0 = 6*cb;
    const int row0 = 32*bg;

    const int w    = tid >> 6;
    const int lane = tid & 63;
    const int ks2  = w & 1;              // kb in [ks2*12, ks2*12+12)
    const int mt   = (w >> 1) & 1;
    const int nt   = (w >> 2) & 1;
    const int lr   = lane & 15;
    const int kq   = lane >> 4;
    const int mrow = mt*16 + lr;

    if (tid == 0) ((volatile char*)sPad)[0] = 0;   // keep sPad allocated

    // ---- B fragments (U slice) -> VGPRs, fp16, once: 12 x f16x8 ----
    f16x8 Bf[12];
    {
        const int c = nt*16 + lr;            // gate-col within block, 0..31 (>=24 pad)
        #pragma unroll
        for (int i=0;i<12;i++){
            const int kb = ks2*12 + i;
            f16x8 v = {0,0,0,0,0,0,0,0};
            if (c < 24){
                const int g = c/6, jj = c - 6*g;
                const float* up = U + (size_t)(g*HID + hc0 + jj)*HID + kb*32 + kq*8;
                #pragma unroll
                for (int e=0;e<8;e++) v[e] = (_Float16)up[e];
            }
            Bf[i] = v;
        }
    }

    // ---- owner setup: 192 owners (32 rows x 6 cols), one output each ----
    const bool own = tid < 192;
    const int orow = tid & 31;
    const int oj   = tid >> 5;               // 0..5
    const int ohc  = hc0 + (oj < 6 ? oj : 0);
    float c_state = 0.f;
    float b0=0.f,b1=0.f,b2=0.f,b3=0.f;
    float s_cur=0.f, s_nextF=0.f;
    float xvf0=0.f,xvf1=0.f,xvf2=0.f,xvf3=0.f;
    unsigned xr0=0,xr1=0,xr2=0,xr3=0,snr=0;
    const char *xp0=nullptr,*xp1=nullptr,*xp2=nullptr,*xp3=nullptr,*spp=nullptr;
    if (own){
        b0 = bias[ohc]; b1 = bias[HID+ohc]; b2 = bias[2*HID+ohc]; b3 = bias[3*HID+ohc];
        const size_t trow0 = (size_t)row0 + orow;
        xp0 = (const char*)(xpT + (size_t)(0*HID+ohc)*NROWS + trow0);
        xp1 = (const char*)(xpT + (size_t)(1*HID+ohc)*NROWS + trow0);
        xp2 = (const char*)(xpT + (size_t)(2*HID+ohc)*NROWS + trow0);
        xp3 = (const char*)(xpT + (size_t)(3*HID+ohc)*NROWS + trow0);
        spp = (const char*)(s_all + ohc);
        // preload t=0 state: xv(0), s(0), s(1)
        xvf0 = (float)*(const _Float16*)xp0;
        xvf1 = (float)*(const _Float16*)xp1;
        xvf2 = (float)*(const _Float16*)xp2;
        xvf3 = (float)*(const _Float16*)xp3;
        s_cur   = s_all[ohc];
        s_nextF = s_all[HID + ohc];
    }
    __syncthreads();

    for (int t = 0; t < T_STEPS; ++t){
        const char* gsrc = hbuf + (size_t)(t&1)*DBUFB + (size_t)bg*HPLANE;

        // ---- A fragments: 12 direct uncached loads (h(t) guaranteed by barrier) ----
        f32x4 ar[12];
        #pragma unroll
        for (int i=0;i<12;i++){
            const int kb = ks2*12 + i;
            const char* ap = gsrc + (size_t)(((kb*4 + kq)*32 + mrow)*16);
            asm volatile("global_load_dwordx4 %0, %1, off sc0 sc1" : "=v"(ar[i]) : "v"(ap));
        }
        asm volatile("s_waitcnt vmcnt(0)"
            : "+v"(ar[0]),"+v"(ar[1]),"+v"(ar[2]),"+v"(ar[3]),"+v"(ar[4]),"+v"(ar[5]),
              "+v"(ar[6]),"+v"(ar[7]),"+v"(ar[8]),"+v"(ar[9]),"+v"(ar[10]),"+v"(ar[11])
            :: "memory");
        __builtin_amdgcn_sched_barrier(0);

        // ---- 12 MFMAs: 2 chains of 6, summed ----
        f32x4 acA = {0.f,0.f,0.f,0.f};
        f32x4 acB = {0.f,0.f,0.f,0.f};
        #pragma unroll
        for (int i=0;i<6;i++){
            acA = __builtin_amdgcn_mfma_f32_16x16x32_f16(
                      __builtin_bit_cast(f16x8, ar[i]),   Bf[i],   acA, 0,0,0);
            acB = __builtin_amdgcn_mfma_f32_16x16x32_f16(
                      __builtin_bit_cast(f16x8, ar[6+i]), Bf[6+i], acB, 0,0,0);
        }
        f32x4 acc = acA + acB;

        // ---- K-split partial to LDS (vector store, stride 33 — r1-proven) ----
        {
            float* rp = sRed + (size_t)(ks2*32 + nt*16 + lr)*33 + mt*16 + kq*4;
            *(f32x4*)rp = acc;
        }
        __syncthreads();

        // ---- pointwise LSTM update (192 owners, 1 value each) ----
        if (own){
            if (t){   // consume barrier-prefetched values
                s_cur   = s_nextF;
                s_nextF = __builtin_bit_cast(float, snr);
                xvf0 = h16_to_f(xr0); xvf1 = h16_to_f(xr1);
                xvf2 = h16_to_f(xr2); xvf3 = h16_to_f(xr3);
            }
            const int c0_ = 0*6 + oj, c1_ = 1*6 + oj, c2_ = 2*6 + oj, c3_ = 3*6 + oj;
            float p0 = xvf0 + b0 + sRed[(size_t)c0_*33 + orow] + sRed[(size_t)(32+c0_)*33 + orow];
            float p1 = xvf1 + b1 + sRed[(size_t)c1_*33 + orow] + sRed[(size_t)(32+c1_)*33 + orow];
            float p2 = xvf2 + b2 + sRed[(size_t)c2_*33 + orow] + sRed[(size_t)(32+c2_)*33 + orow];
            float p3 = xvf3 + b3 + sRed[(size_t)c3_*33 + orow] + sRed[(size_t)(32+c3_)*33 + orow];
            const float s = s_cur;
            p0 *= s; p1 *= s; p2 *= s; p3 *= s;
            float ig = sigmoidf_(p0)*s;
            float fg = sigmoidf_(p1)*s;
            float cg = tanhf(p2)*s;
            float og = sigmoidf_(p3)*s;
            c_state = fg*c_state + ig*cg;
            float h = og*tanhf(c_state);
            out[((size_t)t*BATCH + row0 + orow)*HID + ohc] = h;
            if (t+1 < T_STEPS){
                float hs = h * s_nextF;           // h(t+1 input) pre-scaled by s(t+1)
                unsigned int hv = f16_bits(hs);
                char* dst = hbuf + (size_t)((t+1)&1)*DBUFB + (size_t)bg*HPLANE
                          + 2*(size_t)(((ohc>>3)*32 + orow)*8 + (ohc&7));
                asm volatile("global_store_short %0, %1, off sc0 sc1"
                             :: "v"(dst), "v"(hv) : "memory");
            }
        }

        // ---- barrier + next-step prefetch (r0-proven striped counters) ----
        if (t+1 < T_STEPS){
            asm volatile("s_waitcnt vmcnt(0)" ::: "memory");  // h stores at MALL
            __syncthreads();
            // prefetch xv(t+1) + s(t+2) under the barrier wait
            if (own){
                const size_t off = (size_t)(t+1)*BATCH*2;     // bytes: +64 rows/step
                const int ts = (t+2 < T_STEPS) ? (t+2) : (T_STEPS-1);
                const char* sp = spp + (size_t)ts*HID*4;
                asm volatile("global_load_ushort %0, %1, off" : "=v"(xr0) : "v"(xp0 + off));
                asm volatile("global_load_ushort %0, %1, off" : "=v"(xr1) : "v"(xp1 + off));
                asm volatile("global_load_ushort %0, %1, off" : "=v"(xr2) : "v"(xp2 + off));
                asm volatile("global_load_ushort %0, %1, off" : "=v"(xr3) : "v"(xp3 + off));
                asm volatile("global_load_dword %0, %1, off"  : "=v"(snr) : "v"(sp));
            }
            if (tid == 0){
                const unsigned cell = (unsigned)((bg*4 + (cb&3))*32);
                __hip_atomic_fetch_add(bar + cell, 1u, __ATOMIC_RELAXED, __HIP_MEMORY_SCOPE_AGENT);
                const unsigned tgt = (unsigned)(t+1)*128u;
                for (;;){
                    unsigned ssum = 0;
                    #pragma unroll
                    for (int c2=0;c2<4;c2++)
                        ssum += __hip_atomic_load(bar + (bg*4+c2)*32, __ATOMIC_RELAXED, __HIP_MEMORY_SCOPE_AGENT);
                    if (ssum >= tgt) break;
                    __builtin_amdgcn_s_sleep(1);
                }
            }
            __syncthreads();
        }
    }
}

extern "C" void kernel_launch(void* const* d_in, const int* in_sizes, int n_in,
                              void* d_out, int out_size, void* d_ws, size_t ws_size,
                              hipStream_t stream){
    const float* x  = (const float*)d_in[0];
    const float* W  = (const float*)d_in[1];
    const float* U  = (const float*)d_in[2];
    const float* b  = (const float*)d_in[3];
    const float* la = (const float*)d_in[4];
    const float* u  = (const float*)d_in[5];
    float* out = (float*)d_out;

    char* ws = (char*)d_ws;
    char*           hbuf  = ws;                                       // 196608 B (2 slots)
    unsigned int*   bar   = (unsigned int*)(ws + 196608);             // 1024 B used
    _Float16*       xf16  = (_Float16*)(ws + 200704);                 // 33554432 B
    float*          s_all = (float*)(ws + 200704);                    // 1572864 B, aliases xf16
    _Float16*       wf16  = (_Float16*)(ws + 200704 + 33554432);      // 3145728 B
    unsigned short* xpT   = (unsigned short*)(ws + 36900864);         // 201326592 B
    // total 238227456 B <= proven footprint. s_all aliases xf16: xf16 is dead
    // after xproj_gemm_t; gate_s_kernel runs after it on the same stream.

    hipMemsetAsync(d_ws, 0, 200704, stream);   // zero hbuf (h0=0) + barrier

    cvt_f16_kernel<<<65536, 256, 0, stream>>>(x, xf16, NROWS*IN_DIM);
    cvt_f16_kernel<<<6144,  256, 0, stream>>>(W, wf16, G4H*IN_DIM);
    xproj_gemm_t<<<6144, 256, 0, stream>>>(xf16, wf16, xpT);
    gate_s_kernel<<<1536, 256, 0, stream>>>(u, la, s_all, T_STEPS*HID);
    lstm_scan11<<<256, 512, 0, stream>>>(U, b, s_all, (const _Float16*)xpT, out, hbuf, bar);
}